// Round 10
// baseline (54.084 us; speedup 1.0000x reference)
//
#include <hip/hip_runtime.h>

typedef __attribute__((ext_vector_type(8))) short bf16x8;
typedef __attribute__((ext_vector_type(4))) float f32x4;
typedef __attribute__((ext_vector_type(4))) ushort u16x4;

#define C_DIM 256
#define S_DIM 512
#define P_DIM 128
#define K_DIM 512
#define INV_BW 20.0f
#define EPS_LOSS 1e-5f

// ws layout (float offsets) — every cell overwritten each call
#define OFF_SS2    0          // [2][512] fp32 sumsq t2
#define OFF_SS1    1024       // [2][512] fp32 sumsq t1
#define OFF_DIAG   2048       // [2][512] fp32 diag of E
#define OFF_CNTBF  3072       // ushort[128][512] = 32768 float slots
#define OFF_T2BF   35840      // ushort[2][512][256] = 131072 float slots
#define OFF_T1BF   166912     // ushort[2][512][256]
#define OFF_EBF    297984     // ushort[2][512][512] = 262144 float slots
#define OFF_ETBF   560128     // ushort[2][512][512]
#define OFF_D1     822272     // float[2 h][128 p][2 b][512]
#define OFF_D2     1084416    // float[2 h][128 p][2 b][512]
#define OFF_PART   1346560    // float[256]
#define OFF_BAR    1346816    // int[3]: barA, barB, loss ticket (re-armed by pre)

__device__ inline ushort f2bf(float f) {   // RNE float->bf16 (finite inputs)
  union { float f; uint u; } v; v.f = f;
  return (ushort)((v.u + 0x7FFF + ((v.u >> 16) & 1)) >> 16);
}

// Single-use grid barrier (re-armed by pre_kernel each call).
__device__ inline void grid_barrier(int* c, int n) {
  __syncthreads();
  if (threadIdx.x == 0) {
    __builtin_amdgcn_fence(__ATOMIC_RELEASE, "agent");
    __hip_atomic_fetch_add(c, 1, __ATOMIC_RELAXED, __HIP_MEMORY_SCOPE_AGENT);
    while (__hip_atomic_load(c, __ATOMIC_RELAXED, __HIP_MEMORY_SCOPE_AGENT) < n)
      __builtin_amdgcn_s_sleep(2);
    __builtin_amdgcn_fence(__ATOMIC_ACQUIRE, "agent");
  }
  __syncthreads();
}

// K1: blocks 0..127  -> bf16 transpose + sumsq; one (tensor,b,16-row stripe) each
//     blocks 128..255 -> per-patch histogram -> bf16 cnt[p][s]; re-arms barriers
#define TP 260
__global__ __launch_bounds__(256) void pre_kernel(
    const float* __restrict__ t2, const float* __restrict__ t1,
    const int* __restrict__ idx,
    float* __restrict__ ss2, float* __restrict__ ss1,
    ushort* __restrict__ t2bfT, ushort* __restrict__ t1bfT,
    ushort* __restrict__ cntbf, int* __restrict__ bar) {
  int blk = blockIdx.x, tid = threadIdx.x;
  if (blk < 128) {
    __shared__ ushort tl[16][TP];
    __shared__ float ps[16][17];
    int tt = blk >> 6, b = (blk >> 5) & 1, stile = blk & 31;
    int s0 = stile * 16;
    const float* src = (tt ? t1 : t2) + b * (C_DIM * S_DIM);
    ushort* dst = (tt ? t1bfT : t2bfT) + b * (S_DIM * C_DIM);
    float* ssd = (tt ? ss1 : ss2) + b * S_DIM;
    int ls = tid & 15, cg = tid >> 4;
    float a = 0.f;
    #pragma unroll
    for (int k = 0; k < 16; ++k) {
      int c = cg + 16 * k;
      float v = src[c * S_DIM + s0 + ls];
      a += v * v;
      tl[ls][c] = f2bf(v);
    }
    ps[cg][ls] = a;
    __syncthreads();
    if (tid < 16) {
      float ss = 0.f;
      #pragma unroll
      for (int j = 0; j < 16; ++j) ss += ps[j][tid];
      ssd[s0 + tid] = ss;
    }
    int wv = tid >> 6, ln = tid & 63;
    #pragma unroll
    for (int i = 0; i < 4; ++i) {
      int sl = wv * 4 + i;
      u16x4 pk = *reinterpret_cast<const u16x4*>(&tl[sl][ln * 4]);
      *reinterpret_cast<u16x4*>(&dst[(s0 + sl) * C_DIM + ln * 4]) = pk;
    }
  } else {
    __shared__ int c_lds[S_DIM];
    int p = blk - 128;
    if (blk == 128 && tid < 3) bar[tid] = 0;   // re-arm barriers + ticket
    c_lds[tid] = 0; c_lds[tid + 256] = 0;
    __syncthreads();
    atomicAdd(&c_lds[idx[p * K_DIM + tid]], 1);
    atomicAdd(&c_lds[idx[p * K_DIM + tid + 256]], 1);
    __syncthreads();
    cntbf[p * S_DIM + tid]       = f2bf((float)c_lds[tid]);
    cntbf[p * S_DIM + tid + 256] = f2bf((float)c_lds[tid + 256]);
  }
}

// K2: fused gemm_exp -> [grid barrier] -> denom -> [grid barrier] -> loss.
// 256 blocks x 512 thr (1 block/CU -> co-resident). Phase bodies and wave-job
// decomposition identical to R5's three kernels (2048 wave-jobs per phase).
__global__ __launch_bounds__(512) void fused_kernel(
    const ushort* __restrict__ t2bfT, const ushort* __restrict__ t1bfT,
    const float* __restrict__ ss2, const float* __restrict__ ss1,
    const ushort* __restrict__ cntbf, const int* __restrict__ idx,
    ushort* __restrict__ Ebf, ushort* __restrict__ ETbf,
    float* __restrict__ D1, float* __restrict__ D2, float* __restrict__ diag,
    float* __restrict__ part2, int* __restrict__ bar, float* __restrict__ out) {
  int blk = blockIdx.x, tid = threadIdx.x;
  int wave = tid >> 6, lane = tid & 63;
  int lr = lane & 15, lo = lane >> 4;

  // ---- Phase A: Gram+exp -> Ebf, ETbf, diag (job = one 16x16 (s,t) tile) ----
  {
    int job = blk * 8 + wave;               // 0..2047
    int n = job & 31, m = (job >> 5) & 31, b = job >> 10;
    int m0 = m * 16, c0 = n * 16;
    const ushort* ap = t2bfT + b * (S_DIM * C_DIM) + (m0 + lr) * C_DIM + lo * 8;
    const ushort* bp = t1bfT + b * (S_DIM * C_DIM) + (c0 + lr) * C_DIM + lo * 8;
    f32x4 acc = {0.f, 0.f, 0.f, 0.f};
    #pragma unroll
    for (int k = 0; k < 8; ++k) {
      bf16x8 af = *reinterpret_cast<const bf16x8*>(ap + k * 32);
      bf16x8 bv = *reinterpret_cast<const bf16x8*>(bp + k * 32);
      acc = __builtin_amdgcn_mfma_f32_16x16x32_bf16(af, bv, acc, 0, 0, 0);
    }
    float bs = 1.0f / fmaxf(sqrtf(ss1[b * S_DIM + c0 + lr]), 1e-12f);
    float e[4]; ushort eb[4];
    ushort* Eb  = Ebf  + b * (S_DIM * S_DIM);
    ushort* ETb = ETbf + b * (S_DIM * S_DIM);
    #pragma unroll
    for (int r = 0; r < 4; ++r) {
      int row = m0 + lo * 4 + r;
      float as = 1.0f / fmaxf(sqrtf(ss2[b * S_DIM + row]), 1e-12f);
      e[r] = expf(acc[r] * as * bs * INV_BW);
      eb[r] = f2bf(e[r]);
      Eb[row * S_DIM + c0 + lr] = eb[r];
    }
    u16x4 pk = {eb[0], eb[1], eb[2], eb[3]};
    *reinterpret_cast<u16x4*>(&ETb[(c0 + lr) * S_DIM + m0 + lo * 4]) = pk;
    if (m == n && (lr >> 2) == lo) diag[b * S_DIM + m0 + lr] = e[lr & 3];
  }
  grid_barrier(&bar[0], 256);

  // ---- Phase B: MFMA denominators; h-partials to disjoint buffers ----
  {
    int job = blk * 8 + wave;               // 0..2047
    int n = job & 31, m = (job >> 5) & 7, b = (job >> 8) & 1;
    int z = (job >> 9) & 1, h = job >> 10;
    int m0 = m * 16, col0 = n * 16;
    const ushort* Bmat = (z ? Ebf : ETbf) + b * (S_DIM * S_DIM);
    const ushort* aptr = cntbf + (m0 + lr) * S_DIM + h * 256 + lo * 8;
    const ushort* bptr = Bmat + (col0 + lr) * S_DIM + h * 256 + lo * 8;
    f32x4 acc = {0.f, 0.f, 0.f, 0.f};
    #pragma unroll
    for (int k = 0; k < 8; ++k) {
      bf16x8 af = *reinterpret_cast<const bf16x8*>(aptr + k * 32);
      bf16x8 bv = *reinterpret_cast<const bf16x8*>(bptr + k * 32);
      acc = __builtin_amdgcn_mfma_f32_16x16x32_bf16(af, bv, acc, 0, 0, 0);
    }
    float* Dp = (z ? D2 : D1);
    #pragma unroll
    for (int r = 0; r < 4; ++r) {
      int p = m0 + lo * 4 + r;
      Dp[((h * P_DIM + p) * 2 + b) * S_DIM + col0 + lr] = acc[r];
    }
  }
  grid_barrier(&bar[1], 256);

  // ---- Phase C: loss terms + last-arriver deterministic final reduction ----
  {
    const int HOFF = P_DIM * 2 * S_DIM;
    int p = blk >> 1, kh = blk & 1;
    int b = tid >> 8, kk = kh * 256 + (tid & 255);
    int s = idx[p * K_DIM + kk];
    float pos = diag[b * S_DIM + s];
    int o = (p * 2 + b) * S_DIM + s;
    float d1 = D1[o] + D1[HOFF + o];
    float d2 = D2[o] + D2[HOFF + o];
    float term = logf(0.5f * (pos / d1 + pos / d2) + EPS_LOSS);
    for (int off = 32; off; off >>= 1) term += __shfl_down(term, off);
    __shared__ float red[8];
    __shared__ int lastflag;
    if (lane == 0) red[wave] = term;
    __syncthreads();
    if (tid == 0) {
      float tsum = 0.f;
      #pragma unroll
      for (int i = 0; i < 8; ++i) tsum += red[i];
      atomicExch(&part2[blk], tsum);
      __builtin_amdgcn_fence(__ATOMIC_RELEASE, "agent");
      int old = __hip_atomic_fetch_add(&bar[2], 1, __ATOMIC_ACQ_REL,
                                       __HIP_MEMORY_SCOPE_AGENT);
      lastflag = (old == 255);
    }
    __syncthreads();
    if (lastflag) {
      if (tid == 0) __builtin_amdgcn_fence(__ATOMIC_ACQUIRE, "agent");
      __syncthreads();
      float v = (tid < 256)
          ? __hip_atomic_load(&part2[tid], __ATOMIC_RELAXED,
                              __HIP_MEMORY_SCOPE_AGENT) : 0.f;
      for (int off = 32; off; off >>= 1) v += __shfl_down(v, off);
      __shared__ float red2[8];
      if (lane == 0) red2[wave] = v;
      __syncthreads();
      if (tid == 0) {
        float tsum = 0.f;
        #pragma unroll
        for (int i = 0; i < 8; ++i) tsum += red2[i];
        out[0] = -tsum * (1.0f / (P_DIM * 2.0f * K_DIM));
      }
    }
  }
}

extern "C" void kernel_launch(void* const* d_in, const int* in_sizes, int n_in,
                              void* d_out, int out_size, void* d_ws, size_t ws_size,
                              hipStream_t stream) {
  const float* t2 = (const float*)d_in[0];
  const float* t1 = (const float*)d_in[1];
  const int* idx  = (const int*)d_in[2];
  float* ws = (float*)d_ws;
  float*  ss2    = ws + OFF_SS2;
  float*  ss1    = ws + OFF_SS1;
  float*  diag   = ws + OFF_DIAG;
  ushort* cntbf  = (ushort*)(ws + OFF_CNTBF);
  ushort* t2bfT  = (ushort*)(ws + OFF_T2BF);
  ushort* t1bfT  = (ushort*)(ws + OFF_T1BF);
  ushort* Ebf    = (ushort*)(ws + OFF_EBF);
  ushort* ETbf   = (ushort*)(ws + OFF_ETBF);
  float*  D1     = ws + OFF_D1;
  float*  D2     = ws + OFF_D2;
  float*  part2  = ws + OFF_PART;
  int*    bar    = (int*)(ws + OFF_BAR);

  pre_kernel<<<256, 256, 0, stream>>>(t2, t1, idx, ss2, ss1, t2bfT, t1bfT,
                                      cntbf, bar);
  fused_kernel<<<256, 512, 0, stream>>>(t2bfT, t1bfT, ss2, ss1, cntbf, idx,
                                        Ebf, ETbf, D1, D2, diag, part2, bar,
                                        (float*)d_out);
}

// Round 11
// 30.084 us; speedup vs baseline: 1.7978x; 1.7978x over previous
//
#include <hip/hip_runtime.h>

typedef __attribute__((ext_vector_type(8))) short bf16x8;
typedef __attribute__((ext_vector_type(4))) float f32x4;
typedef __attribute__((ext_vector_type(4))) ushort u16x4;

#define C_DIM 256
#define S_DIM 512
#define P_DIM 128
#define K_DIM 512
#define INV_BW 20.0f
#define EPS_LOSS 1e-5f

// ws layout (float offsets) — every cell overwritten each call
#define OFF_SS2    0          // [2][512] fp32 sumsq t2
#define OFF_SS1    1024       // [2][512] fp32 sumsq t1
#define OFF_DIAG   2048       // [2][512] fp32 diag of E
#define OFF_CNTBF  3072       // ushort[128][512] = 32768 float slots
#define OFF_T2BF   35840      // ushort[2][512][256] = 131072 float slots
#define OFF_T1BF   166912     // ushort[2][512][256]
#define OFF_EBF    297984     // ushort[2][512][512] = 262144 float slots
#define OFF_ETBF   560128     // ushort[2][512][512]
#define OFF_D1     822272     // float[2 h][128 p][2 b][512]
#define OFF_D2     1084416    // float[2 h][128 p][2 b][512]
#define OFF_PART   1346560    // float[128]
#define OFF_BAR    1346816    // int[3]: [2] = loss ticket (re-armed by pre)

__device__ inline ushort f2bf(float f) {   // RNE float->bf16 (finite inputs)
  union { float f; uint u; } v; v.f = f;
  return (ushort)((v.u + 0x7FFF + ((v.u >> 16) & 1)) >> 16);
}

// K1: blocks 0..127  -> bf16 transpose + sumsq; one (tensor,b,16-row stripe) each
//     blocks 128..255 -> per-patch histogram -> bf16 cnt[p][s]; re-arms ticket
#define TP 260
__global__ __launch_bounds__(256) void pre_kernel(
    const float* __restrict__ t2, const float* __restrict__ t1,
    const int* __restrict__ idx,
    float* __restrict__ ss2, float* __restrict__ ss1,
    ushort* __restrict__ t2bfT, ushort* __restrict__ t1bfT,
    ushort* __restrict__ cntbf, int* __restrict__ bar) {
  int blk = blockIdx.x, tid = threadIdx.x;
  if (blk < 128) {
    __shared__ ushort tl[16][TP];
    __shared__ float ps[16][17];
    int tt = blk >> 6, b = (blk >> 5) & 1, stile = blk & 31;
    int s0 = stile * 16;
    const float* src = (tt ? t1 : t2) + b * (C_DIM * S_DIM);
    ushort* dst = (tt ? t1bfT : t2bfT) + b * (S_DIM * C_DIM);
    float* ssd = (tt ? ss1 : ss2) + b * S_DIM;
    int ls = tid & 15, cg = tid >> 4;
    float a = 0.f;
    #pragma unroll
    for (int k = 0; k < 16; ++k) {
      int c = cg + 16 * k;
      float v = src[c * S_DIM + s0 + ls];
      a += v * v;
      tl[ls][c] = f2bf(v);
    }
    ps[cg][ls] = a;
    __syncthreads();
    if (tid < 16) {
      float ss = 0.f;
      #pragma unroll
      for (int j = 0; j < 16; ++j) ss += ps[j][tid];
      ssd[s0 + tid] = ss;
    }
    int wv = tid >> 6, ln = tid & 63;
    #pragma unroll
    for (int i = 0; i < 4; ++i) {
      int sl = wv * 4 + i;
      u16x4 pk = *reinterpret_cast<const u16x4*>(&tl[sl][ln * 4]);
      *reinterpret_cast<u16x4*>(&dst[(s0 + sl) * C_DIM + ln * 4]) = pk;
    }
  } else {
    __shared__ int c_lds[S_DIM];
    int p = blk - 128;
    if (blk == 128 && tid < 3) bar[tid] = 0;   // re-arm ticket each call
    c_lds[tid] = 0; c_lds[tid + 256] = 0;
    __syncthreads();
    atomicAdd(&c_lds[idx[p * K_DIM + tid]], 1);
    atomicAdd(&c_lds[idx[p * K_DIM + tid + 256]], 1);
    __syncthreads();
    cntbf[p * S_DIM + tid]       = f2bf((float)c_lds[tid]);
    cntbf[p * S_DIM + tid + 256] = f2bf((float)c_lds[tid + 256]);
  }
}

// K2: MFMA Gram + exp. Per wave: TWO 16x16 (s,t) tiles sharing preloaded
// B-fragments (K=256, 8 MFMA each, independent chains -> ILP). Epilogue:
// fused scale + __expf, bf16 E + packed ET + fp32 diag.
__global__ __launch_bounds__(256) void gemm_exp_mfma_kernel(
    const ushort* __restrict__ t2bfT, const ushort* __restrict__ t1bfT,
    const float* __restrict__ ss2, const float* __restrict__ ss1,
    ushort* __restrict__ Ebf, ushort* __restrict__ ETbf,
    float* __restrict__ diag) {
  int wave = threadIdx.x >> 6, lane = threadIdx.x & 63;
  int job = blockIdx.x * 4 + wave;          // 0..1023
  int n = job & 31, mp = (job >> 5) & 15, b = job >> 9;
  int c0 = n * 16;
  int lr = lane & 15, lo = lane >> 4;
  const ushort* base2 = t2bfT + b * (S_DIM * C_DIM);
  const ushort* bp = t1bfT + b * (S_DIM * C_DIM) + (c0 + lr) * C_DIM + lo * 8;
  bf16x8 bfr[8];
  #pragma unroll
  for (int k = 0; k < 8; ++k)
    bfr[k] = *reinterpret_cast<const bf16x8*>(bp + k * 32);
  float bs = 1.0f / fmaxf(sqrtf(ss1[b * S_DIM + c0 + lr]), 1e-12f);
  ushort* Eb  = Ebf  + b * (S_DIM * S_DIM);
  ushort* ETb = ETbf + b * (S_DIM * S_DIM);
  #pragma unroll
  for (int t = 0; t < 2; ++t) {
    int m0 = mp * 32 + t * 16;
    const ushort* ap = base2 + (m0 + lr) * C_DIM + lo * 8;
    f32x4 acc = {0.f, 0.f, 0.f, 0.f};
    #pragma unroll
    for (int k = 0; k < 8; ++k) {
      bf16x8 af = *reinterpret_cast<const bf16x8*>(ap + k * 32);
      acc = __builtin_amdgcn_mfma_f32_16x16x32_bf16(af, bfr[k], acc, 0, 0, 0);
    }
    float e[4]; ushort eb[4];
    #pragma unroll
    for (int r = 0; r < 4; ++r) {
      int row = m0 + lo * 4 + r;
      float as = 1.0f / fmaxf(sqrtf(ss2[b * S_DIM + row]), 1e-12f);
      e[r] = __expf(acc[r] * as * bs * INV_BW);
      eb[r] = f2bf(e[r]);
      Eb[row * S_DIM + c0 + lr] = eb[r];
    }
    u16x4 pk = {eb[0], eb[1], eb[2], eb[3]};
    *reinterpret_cast<u16x4*>(&ETb[(c0 + lr) * S_DIM + m0 + lo * 4]) = pk;
    if (m0 == c0 && (lr >> 2) == lo) diag[b * S_DIM + m0 + lr] = e[lr & 3];
  }
}

// K3: MFMA denominators. Per wave: TWO 16-col tiles sharing preloaded
// A-fragments (cnt rows). D1 from ETbf, D2 from Ebf; K split in 2 halves.
__global__ __launch_bounds__(256) void denom_mfma_kernel(
    const ushort* __restrict__ Ebf, const ushort* __restrict__ ETbf,
    const ushort* __restrict__ cntbf,
    float* __restrict__ D1, float* __restrict__ D2) {
  int wave = threadIdx.x >> 6, lane = threadIdx.x & 63;
  int job = blockIdx.x * 4 + wave;          // 0..1023
  int np = job & 15, m = (job >> 4) & 7, b = (job >> 7) & 1;
  int z = (job >> 8) & 1, h = job >> 9;
  int m0 = m * 16;
  int lr = lane & 15, lo = lane >> 4;
  const ushort* Bmat = (z ? Ebf : ETbf) + b * (S_DIM * S_DIM);
  float* Dp = (z ? D2 : D1);
  const ushort* aptr = cntbf + (m0 + lr) * S_DIM + h * 256 + lo * 8;
  bf16x8 afr[8];
  #pragma unroll
  for (int k = 0; k < 8; ++k)
    afr[k] = *reinterpret_cast<const bf16x8*>(aptr + k * 32);
  #pragma unroll
  for (int t = 0; t < 2; ++t) {
    int col0 = np * 32 + t * 16;
    const ushort* bptr = Bmat + (col0 + lr) * S_DIM + h * 256 + lo * 8;
    f32x4 acc = {0.f, 0.f, 0.f, 0.f};
    #pragma unroll
    for (int k = 0; k < 8; ++k) {
      bf16x8 bv = *reinterpret_cast<const bf16x8*>(bptr + k * 32);
      acc = __builtin_amdgcn_mfma_f32_16x16x32_bf16(afr[k], bv, acc, 0, 0, 0);
    }
    #pragma unroll
    for (int r = 0; r < 4; ++r) {
      int p = m0 + lo * 4 + r;
      Dp[((h * P_DIM + p) * 2 + b) * S_DIM + col0 + lr] = acc[r];
    }
  }
}

// K4: loss terms + last-arriver deterministic final reduction.
__global__ __launch_bounds__(512) void loss_final_kernel(
    const int* __restrict__ idx, const float* __restrict__ diag,
    const float* __restrict__ D1, const float* __restrict__ D2,
    float* __restrict__ part, int* __restrict__ bar, float* __restrict__ out) {
  const int HOFF = P_DIM * 2 * S_DIM;
  int p = blockIdx.x, k = threadIdx.x;
  int s = idx[p * K_DIM + k];
  float acc = 0.f;
  #pragma unroll
  for (int b = 0; b < 2; ++b) {
    float pos = diag[b * S_DIM + s];
    int o = (p * 2 + b) * S_DIM + s;
    float d1 = D1[o] + D1[HOFF + o];
    float d2 = D2[o] + D2[HOFF + o];
    acc += __logf(0.5f * (pos / d1 + pos / d2) + EPS_LOSS);
  }
  for (int o = 32; o; o >>= 1) acc += __shfl_down(acc, o);
  __shared__ float red[8];
  __shared__ int lastflag;
  if ((k & 63) == 0) red[k >> 6] = acc;
  __syncthreads();
  if (k == 0) {
    float tsum = 0.f;
    #pragma unroll
    for (int i = 0; i < 8; ++i) tsum += red[i];
    atomicExch(&part[p], tsum);
    __threadfence();
    int old = atomicAdd(&bar[2], 1);
    lastflag = (old == P_DIM - 1);
  }
  __syncthreads();
  if (lastflag) {
    __threadfence();
    float v = (k < P_DIM) ? atomicAdd(&part[k], 0.0f) : 0.0f;
    for (int o = 32; o; o >>= 1) v += __shfl_down(v, o);
    __shared__ float red2[8];
    if ((k & 63) == 0) red2[k >> 6] = v;
    __syncthreads();
    if (k == 0) {
      float tsum = 0.f;
      #pragma unroll
      for (int i = 0; i < 8; ++i) tsum += red2[i];
      out[0] = -tsum * (1.0f / (P_DIM * 2.0f * K_DIM));
    }
  }
}

extern "C" void kernel_launch(void* const* d_in, const int* in_sizes, int n_in,
                              void* d_out, int out_size, void* d_ws, size_t ws_size,
                              hipStream_t stream) {
  const float* t2 = (const float*)d_in[0];
  const float* t1 = (const float*)d_in[1];
  const int* idx  = (const int*)d_in[2];
  float* ws = (float*)d_ws;
  float*  ss2    = ws + OFF_SS2;
  float*  ss1    = ws + OFF_SS1;
  float*  diag   = ws + OFF_DIAG;
  ushort* cntbf  = (ushort*)(ws + OFF_CNTBF);
  ushort* t2bfT  = (ushort*)(ws + OFF_T2BF);
  ushort* t1bfT  = (ushort*)(ws + OFF_T1BF);
  ushort* Ebf    = (ushort*)(ws + OFF_EBF);
  ushort* ETbf   = (ushort*)(ws + OFF_ETBF);
  float*  D1     = ws + OFF_D1;
  float*  D2     = ws + OFF_D2;
  float*  part   = ws + OFF_PART;
  int*    bar    = (int*)(ws + OFF_BAR);

  pre_kernel<<<256, 256, 0, stream>>>(t2, t1, idx, ss2, ss1, t2bfT, t1bfT,
                                      cntbf, bar);
  gemm_exp_mfma_kernel<<<256, 256, 0, stream>>>(t2bfT, t1bfT, ss2, ss1,
                                                Ebf, ETbf, diag);
  denom_mfma_kernel<<<256, 256, 0, stream>>>(Ebf, ETbf, cntbf, D1, D2);
  loss_final_kernel<<<P_DIM, 512, 0, stream>>>(idx, diag, D1, D2, part, bar,
                                               (float*)d_out);
}

// Round 12
// 29.369 us; speedup vs baseline: 1.8415x; 1.0243x over previous
//
#include <hip/hip_runtime.h>

typedef __attribute__((ext_vector_type(8))) short bf16x8;
typedef __attribute__((ext_vector_type(4))) float f32x4;
typedef __attribute__((ext_vector_type(4))) ushort u16x4;

#define C_DIM 256
#define S_DIM 512
#define P_DIM 128
#define K_DIM 512
#define INV_BW 20.0f
#define EPS_LOSS 1e-5f

// ws layout (float offsets) — every cell overwritten each call
#define OFF_DIAG   0          // [2][512] fp32 diag of E
#define OFF_EBF    1024       // ushort[2][512][512] = 262144 float slots
#define OFF_ETBF   263168     // ushort[2][512][512]
#define OFF_D1     525312     // float[128 p][2 b][512 t]
#define OFF_D2     656384     // float[128 p][2 b][512 s]
#define OFF_PART   787456     // float[128]
#define OFF_BAR    787584     // int[1] loss ticket (re-armed by gram blk 0)

__device__ inline ushort f2bf(float f) {   // RNE float->bf16 (finite inputs)
  union { float f; uint u; } v; v.f = f;
  return (ushort)((v.u + 0x7FFF + ((v.u >> 16) & 1)) >> 16);
}
__device__ inline float bf2f(ushort u) {
  union { uint u; float f; } v; v.u = ((uint)u) << 16;
  return v.f;
}

// K1: self-staging Gram+exp. Block = 32x32 E-tile region for batch b.
// Stage: thread c loads 32 m-rows + 32 c-rows of fp32 (float4), converts to
// bf16 into transposed LDS panels. Sumsq per staged row in-block (threads
// 0..63). 4 waves x (2x2 tiles) x K=256 MFMA from LDS. Epilogue: scale,
// __expf, write bf16 E + packed ET + fp32 diag. Block 0 re-arms loss ticket.
__global__ __launch_bounds__(256) void gram_exp_kernel(
    const float* __restrict__ t2, const float* __restrict__ t1,
    ushort* __restrict__ Ebf, ushort* __restrict__ ETbf,
    float* __restrict__ diag, int* __restrict__ bar) {
  __shared__ ushort A_[32][264];   // [s-local][c] bf16 of t2 panel
  __shared__ ushort B_[32][264];   // [t-local][c] bf16 of t1 panel
  __shared__ float sA[32], sB[32];
  int blk = blockIdx.x, tid = threadIdx.x;
  if (blk == 0 && tid == 0) bar[0] = 0;   // re-arm loss ticket each call
  int mb = blk & 15, nb = (blk >> 4) & 15, b = blk >> 8;
  int m0 = mb * 32, c0 = nb * 32;
  // ---- stage both panels (c = tid) ----
  {
    const float* pa = t2 + (b * C_DIM + tid) * S_DIM + m0;
    const float* pb = t1 + (b * C_DIM + tid) * S_DIM + c0;
    #pragma unroll
    for (int q = 0; q < 8; ++q) {
      float4 va = *reinterpret_cast<const float4*>(pa + q * 4);
      float4 vb = *reinterpret_cast<const float4*>(pb + q * 4);
      A_[q * 4 + 0][tid] = f2bf(va.x); A_[q * 4 + 1][tid] = f2bf(va.y);
      A_[q * 4 + 2][tid] = f2bf(va.z); A_[q * 4 + 3][tid] = f2bf(va.w);
      B_[q * 4 + 0][tid] = f2bf(vb.x); B_[q * 4 + 1][tid] = f2bf(vb.y);
      B_[q * 4 + 2][tid] = f2bf(vb.z); B_[q * 4 + 3][tid] = f2bf(vb.w);
    }
  }
  __syncthreads();
  // ---- per-row sumsq of the bf16 panels (threads 0..63) ----
  if (tid < 64) {
    const ushort* row = (tid < 32) ? &A_[tid][0] : &B_[tid - 32][0];
    float a0 = 0.f, a1 = 0.f, a2 = 0.f, a3 = 0.f;
    #pragma unroll
    for (int k = 0; k < 64; ++k) {
      u16x4 v = *reinterpret_cast<const u16x4*>(row + k * 4);
      float x0 = bf2f(v.x), x1 = bf2f(v.y), x2 = bf2f(v.z), x3 = bf2f(v.w);
      a0 += x0 * x0; a1 += x1 * x1; a2 += x2 * x2; a3 += x3 * x3;
    }
    float sc = 1.0f / fmaxf(sqrtf((a0 + a1) + (a2 + a3)), 1e-12f);
    if (tid < 32) sA[tid] = sc; else sB[tid - 32] = sc;
  }
  __syncthreads();
  // ---- MFMA: wave w -> tile (tm = w&1, tn = w>>1) ----
  int wave = tid >> 6, lane = tid & 63;
  int tm = wave & 1, tn = wave >> 1;
  int lr = lane & 15, lo = lane >> 4;
  f32x4 acc = {0.f, 0.f, 0.f, 0.f};
  #pragma unroll
  for (int k = 0; k < 8; ++k) {
    bf16x8 af = *reinterpret_cast<const bf16x8*>(&A_[tm * 16 + lr][lo * 8 + k * 32]);
    bf16x8 bv = *reinterpret_cast<const bf16x8*>(&B_[tn * 16 + lr][lo * 8 + k * 32]);
    acc = __builtin_amdgcn_mfma_f32_16x16x32_bf16(af, bv, acc, 0, 0, 0);
  }
  int mg0 = m0 + tm * 16, cg0 = c0 + tn * 16;
  float bs = sB[tn * 16 + lr];
  ushort* Eb  = Ebf  + b * (S_DIM * S_DIM);
  ushort* ETb = ETbf + b * (S_DIM * S_DIM);
  float e[4]; ushort eb[4];
  #pragma unroll
  for (int r = 0; r < 4; ++r) {
    int rl = tm * 16 + lo * 4 + r;
    float ev = __expf(acc[r] * sA[rl] * bs * INV_BW);
    e[r] = ev; eb[r] = f2bf(ev);
    Eb[(m0 + rl) * S_DIM + cg0 + lr] = eb[r];
  }
  u16x4 pk = {eb[0], eb[1], eb[2], eb[3]};
  *reinterpret_cast<u16x4*>(&ETb[(cg0 + lr) * S_DIM + mg0 + lo * 4]) = pk;
  if (mg0 == cg0 && (lr >> 2) == lo) diag[b * S_DIM + mg0 + lr] = e[lr & 3];
}

// K2: denominators with per-block private histogram. Block = (m: 16 patches,
// ng: 4 col-tiles, b, z). Histogram of idx rows p0..p0+15 in LDS ints ->
// bf16 LDS cnt panel -> 4 waves x 1 col-tile x K=512 (16 MFMA), A from LDS,
// B rows from L2-resident Ebf/ETbf. Single-chain D write (no partials).
__global__ __launch_bounds__(256) void denom_kernel(
    const ushort* __restrict__ Ebf, const ushort* __restrict__ ETbf,
    const int* __restrict__ idx,
    float* __restrict__ D1, float* __restrict__ D2) {
  __shared__ int hist[16][516];
  __shared__ ushort cb[16][520];
  int blk = blockIdx.x, tid = threadIdx.x;
  int m = blk & 7, ng = (blk >> 3) & 7, b = (blk >> 6) & 1, z = blk >> 7;
  int p0 = m * 16;
  #pragma unroll
  for (int i = 0; i < 32; ++i) hist[(tid * 32 + i) >> 9][(tid * 32 + i) & 511] = 0;
  __syncthreads();
  {
    int p = tid >> 4, l16 = tid & 15;
    const int* ip = idx + (p0 + p) * K_DIM + l16;
    #pragma unroll
    for (int j = 0; j < 32; ++j) atomicAdd(&hist[p][ip[j * 16]], 1);
  }
  __syncthreads();
  {
    int p = tid >> 4, l16 = tid & 15;
    #pragma unroll
    for (int j = 0; j < 32; ++j) {
      int col = l16 + j * 16;
      cb[p][col] = f2bf((float)hist[p][col]);
    }
  }
  __syncthreads();
  int wave = tid >> 6, lane = tid & 63;
  int lr = lane & 15, lo = lane >> 4;
  int col0 = (ng * 4 + wave) * 16;
  const ushort* Bmat = (z ? Ebf : ETbf) + b * (S_DIM * S_DIM);
  const ushort* bptr = Bmat + (col0 + lr) * S_DIM + lo * 8;
  f32x4 acc = {0.f, 0.f, 0.f, 0.f};
  #pragma unroll
  for (int k = 0; k < 16; ++k) {
    bf16x8 af = *reinterpret_cast<const bf16x8*>(&cb[lr][lo * 8 + k * 32]);
    bf16x8 bv = *reinterpret_cast<const bf16x8*>(bptr + k * 32);
    acc = __builtin_amdgcn_mfma_f32_16x16x32_bf16(af, bv, acc, 0, 0, 0);
  }
  float* Dp = z ? D2 : D1;
  #pragma unroll
  for (int r = 0; r < 4; ++r) {
    int p = p0 + lo * 4 + r;
    Dp[(p * 2 + b) * S_DIM + col0 + lr] = acc[r];
  }
}

// K3: loss terms + last-arriver deterministic final reduction.
__global__ __launch_bounds__(512) void loss_final_kernel(
    const int* __restrict__ idx, const float* __restrict__ diag,
    const float* __restrict__ D1, const float* __restrict__ D2,
    float* __restrict__ part, int* __restrict__ bar, float* __restrict__ out) {
  int p = blockIdx.x, k = threadIdx.x;
  int s = idx[p * K_DIM + k];
  float acc = 0.f;
  #pragma unroll
  for (int b = 0; b < 2; ++b) {
    float pos = diag[b * S_DIM + s];
    int o = (p * 2 + b) * S_DIM + s;
    float d1 = D1[o];
    float d2 = D2[o];
    acc += __logf(0.5f * (pos / d1 + pos / d2) + EPS_LOSS);
  }
  for (int o = 32; o; o >>= 1) acc += __shfl_down(acc, o);
  __shared__ float red[8];
  __shared__ int lastflag;
  if ((k & 63) == 0) red[k >> 6] = acc;
  __syncthreads();
  if (k == 0) {
    float tsum = 0.f;
    #pragma unroll
    for (int i = 0; i < 8; ++i) tsum += red[i];
    atomicExch(&part[p], tsum);
    __threadfence();
    int old = atomicAdd(&bar[0], 1);
    lastflag = (old == P_DIM - 1);
  }
  __syncthreads();
  if (lastflag) {
    __threadfence();
    float v = (k < P_DIM) ? atomicAdd(&part[k], 0.0f) : 0.0f;
    for (int o = 32; o; o >>= 1) v += __shfl_down(v, o);
    __shared__ float red2[8];
    if ((k & 63) == 0) red2[k >> 6] = v;
    __syncthreads();
    if (k == 0) {
      float tsum = 0.f;
      #pragma unroll
      for (int i = 0; i < 8; ++i) tsum += red2[i];
      out[0] = -tsum * (1.0f / (P_DIM * 2.0f * K_DIM));
    }
  }
}

extern "C" void kernel_launch(void* const* d_in, const int* in_sizes, int n_in,
                              void* d_out, int out_size, void* d_ws, size_t ws_size,
                              hipStream_t stream) {
  const float* t2 = (const float*)d_in[0];
  const float* t1 = (const float*)d_in[1];
  const int* idx  = (const int*)d_in[2];
  float* ws = (float*)d_ws;
  float*  diag   = ws + OFF_DIAG;
  ushort* Ebf    = (ushort*)(ws + OFF_EBF);
  ushort* ETbf   = (ushort*)(ws + OFF_ETBF);
  float*  D1     = ws + OFF_D1;
  float*  D2     = ws + OFF_D2;
  float*  part   = ws + OFF_PART;
  int*    bar    = (int*)(ws + OFF_BAR);

  gram_exp_kernel<<<512, 256, 0, stream>>>(t2, t1, Ebf, ETbf, diag, bar);
  denom_kernel<<<256, 256, 0, stream>>>(Ebf, ETbf, idx, D1, D2);
  loss_final_kernel<<<P_DIM, 512, 0, stream>>>(idx, diag, D1, D2, part, bar,
                                               (float*)d_out);
}

// Round 13
// 29.038 us; speedup vs baseline: 1.8625x; 1.0114x over previous
//
#include <hip/hip_runtime.h>

typedef __attribute__((ext_vector_type(8))) short bf16x8;
typedef __attribute__((ext_vector_type(4))) float f32x4;
typedef __attribute__((ext_vector_type(4))) ushort u16x4;

#define C_DIM 256
#define S_DIM 512
#define P_DIM 128
#define K_DIM 512
#define INV_BW 20.0f
#define EPS_LOSS 1e-5f

// ws layout (float offsets) — every cell overwritten each call
#define OFF_DIAG   0          // [2][512] fp32 diag of E
#define OFF_EBF    1024       // ushort[2][512][512] = 262144 float slots
#define OFF_ETBF   263168     // ushort[2][512][512]
#define OFF_PART   525312     // float[64] per-block loss partials
#define OFF_BAR    525376     // int[1] loss ticket (re-armed by gram blk 0)

__device__ inline ushort f2bf(float f) {   // RNE float->bf16 (finite inputs)
  union { float f; uint u; } v; v.f = f;
  return (ushort)((v.u + 0x7FFF + ((v.u >> 16) & 1)) >> 16);
}
__device__ inline float bf2f(ushort u) {
  union { uint u; float f; } v; v.u = ((uint)u) << 16;
  return v.f;
}

// K1: self-staging Gram+exp (proven in R12, unchanged). Block = 32x32 E-tile.
__global__ __launch_bounds__(256) void gram_exp_kernel(
    const float* __restrict__ t2, const float* __restrict__ t1,
    ushort* __restrict__ Ebf, ushort* __restrict__ ETbf,
    float* __restrict__ diag, int* __restrict__ bar) {
  __shared__ ushort A_[32][264];   // [s-local][c] bf16 of t2 panel
  __shared__ ushort B_[32][264];   // [t-local][c] bf16 of t1 panel
  __shared__ float sA[32], sB[32];
  int blk = blockIdx.x, tid = threadIdx.x;
  if (blk == 0 && tid == 0) bar[0] = 0;   // re-arm loss ticket each call
  int mb = blk & 15, nb = (blk >> 4) & 15, b = blk >> 8;
  int m0 = mb * 32, c0 = nb * 32;
  {
    const float* pa = t2 + (b * C_DIM + tid) * S_DIM + m0;
    const float* pb = t1 + (b * C_DIM + tid) * S_DIM + c0;
    #pragma unroll
    for (int q = 0; q < 8; ++q) {
      float4 va = *reinterpret_cast<const float4*>(pa + q * 4);
      float4 vb = *reinterpret_cast<const float4*>(pb + q * 4);
      A_[q * 4 + 0][tid] = f2bf(va.x); A_[q * 4 + 1][tid] = f2bf(va.y);
      A_[q * 4 + 2][tid] = f2bf(va.z); A_[q * 4 + 3][tid] = f2bf(va.w);
      B_[q * 4 + 0][tid] = f2bf(vb.x); B_[q * 4 + 1][tid] = f2bf(vb.y);
      B_[q * 4 + 2][tid] = f2bf(vb.z); B_[q * 4 + 3][tid] = f2bf(vb.w);
    }
  }
  __syncthreads();
  if (tid < 64) {
    const ushort* row = (tid < 32) ? &A_[tid][0] : &B_[tid - 32][0];
    float a0 = 0.f, a1 = 0.f, a2 = 0.f, a3 = 0.f;
    #pragma unroll
    for (int k = 0; k < 64; ++k) {
      u16x4 v = *reinterpret_cast<const u16x4*>(row + k * 4);
      float x0 = bf2f(v.x), x1 = bf2f(v.y), x2 = bf2f(v.z), x3 = bf2f(v.w);
      a0 += x0 * x0; a1 += x1 * x1; a2 += x2 * x2; a3 += x3 * x3;
    }
    float sc = 1.0f / fmaxf(sqrtf((a0 + a1) + (a2 + a3)), 1e-12f);
    if (tid < 32) sA[tid] = sc; else sB[tid - 32] = sc;
  }
  __syncthreads();
  int wave = tid >> 6, lane = tid & 63;
  int tm = wave & 1, tn = wave >> 1;
  int lr = lane & 15, lo = lane >> 4;
  f32x4 acc = {0.f, 0.f, 0.f, 0.f};
  #pragma unroll
  for (int k = 0; k < 8; ++k) {
    bf16x8 af = *reinterpret_cast<const bf16x8*>(&A_[tm * 16 + lr][lo * 8 + k * 32]);
    bf16x8 bv = *reinterpret_cast<const bf16x8*>(&B_[tn * 16 + lr][lo * 8 + k * 32]);
    acc = __builtin_amdgcn_mfma_f32_16x16x32_bf16(af, bv, acc, 0, 0, 0);
  }
  int mg0 = m0 + tm * 16, cg0 = c0 + tn * 16;
  float bs = sB[tn * 16 + lr];
  ushort* Eb  = Ebf  + b * (S_DIM * S_DIM);
  ushort* ETb = ETbf + b * (S_DIM * S_DIM);
  float e[4]; ushort eb[4];
  #pragma unroll
  for (int r = 0; r < 4; ++r) {
    int rl = tm * 16 + lo * 4 + r;
    float ev = __expf(acc[r] * sA[rl] * bs * INV_BW);
    e[r] = ev; eb[r] = f2bf(ev);
    Eb[(m0 + rl) * S_DIM + cg0 + lr] = eb[r];
  }
  u16x4 pk = {eb[0], eb[1], eb[2], eb[3]};
  *reinterpret_cast<u16x4*>(&ETb[(cg0 + lr) * S_DIM + mg0 + lo * 4]) = pk;
  if (mg0 == cg0 && (lr >> 2) == lo) diag[b * S_DIM + mg0 + lr] = e[lr & 3];
}

// K2: fused denom+loss. Block = (m: 16 patches, b, q: 128-col quarter);
// 64 blocks x 1024 thr (16 waves). LDS histogram -> bf16 cnt (520-pitch) ->
// 16 wave-jobs MFMA K=512 (B from L2 quarter of Ebf/ETbf) -> D1L/D2L in LDS ->
// loss terms filtered s-in-quarter (each term in exactly one block) ->
// partial + ticket; last of 64 reduces. D never touches global.
__global__ __launch_bounds__(1024) void denom_loss_kernel(
    const ushort* __restrict__ Ebf, const ushort* __restrict__ ETbf,
    const int* __restrict__ idx, const float* __restrict__ diag,
    float* __restrict__ part, int* __restrict__ bar, float* __restrict__ out) {
  __shared__ int hist[16][516];
  __shared__ ushort cb[16][520];
  __shared__ float D1L[16][132], D2L[16][132];
  int blk = blockIdx.x, tid = threadIdx.x;
  int m = blk & 7, b = (blk >> 3) & 1, q = blk >> 4;
  int p0 = m * 16;
  int wave = tid >> 6, lane = tid & 63;
  int lr = lane & 15, lo = lane >> 4;
  // ---- histogram of this block's 16 idx rows ----
  {
    int p = tid >> 6, l = tid & 63;
    int* hp = &hist[p][0];
    #pragma unroll
    for (int j = 0; j < 8; ++j) hp[l * 8 + j] = 0;   // p-row zero (516>512 pad ok)
    __syncthreads();
    const int* ip = idx + (p0 + p) * K_DIM + l;
    #pragma unroll
    for (int j = 0; j < 8; ++j) atomicAdd(&hp[ip[j * 64]], 1);
    __syncthreads();
    #pragma unroll
    for (int j = 0; j < 8; ++j) {
      int col = l * 8 + j;
      cb[p][col] = f2bf((float)hp[col]);
    }
  }
  __syncthreads();
  // ---- denominators: wave-job (z = wave>>3, jt = wave&7), K=512 ----
  {
    int z = wave >> 3, jt = wave & 7;
    int col0g = q * 128 + jt * 16, col0l = jt * 16;
    const ushort* Bmat = (z ? Ebf : ETbf) + b * (S_DIM * S_DIM);
    const ushort* bptr = Bmat + (col0g + lr) * S_DIM + lo * 8;
    f32x4 acc = {0.f, 0.f, 0.f, 0.f};
    #pragma unroll
    for (int k = 0; k < 16; ++k) {
      bf16x8 af = *reinterpret_cast<const bf16x8*>(&cb[lr][lo * 8 + k * 32]);
      bf16x8 bv = *reinterpret_cast<const bf16x8*>(bptr + k * 32);
      acc = __builtin_amdgcn_mfma_f32_16x16x32_bf16(af, bv, acc, 0, 0, 0);
    }
    #pragma unroll
    for (int r = 0; r < 4; ++r) {
      int p = lo * 4 + r;
      if (z) D2L[p][col0l + lr] = acc[r];
      else   D1L[p][col0l + lr] = acc[r];
    }
  }
  __syncthreads();
  // ---- loss terms with s in this quarter ----
  {
    int p = tid >> 6, l = tid & 63;
    const int* ip = idx + (p0 + p) * K_DIM + l;
    float acc = 0.f;
    #pragma unroll
    for (int j = 0; j < 8; ++j) {
      int s = ip[j * 64];
      if ((s >> 7) == q) {
        int sl = s & 127;
        float pos = diag[b * S_DIM + s];
        float d1 = D1L[p][sl];
        float d2 = D2L[p][sl];
        acc += __logf(0.5f * (pos / d1 + pos / d2) + EPS_LOSS);
      }
    }
    for (int o = 32; o; o >>= 1) acc += __shfl_down(acc, o);
    __shared__ float red[16];
    __shared__ int lastflag;
    if (lane == 0) red[wave] = acc;
    __syncthreads();
    if (tid == 0) {
      float tsum = 0.f;
      #pragma unroll
      for (int i = 0; i < 16; ++i) tsum += red[i];
      atomicExch(&part[blk], tsum);
      __threadfence();
      int old = atomicAdd(&bar[0], 1);
      lastflag = (old == 63);
    }
    __syncthreads();
    if (lastflag && tid < 64) {
      __threadfence();
      float v = atomicAdd(&part[tid], 0.0f);   // coherent read
      for (int o = 32; o; o >>= 1) v += __shfl_down(v, o);
      if (tid == 0) out[0] = -v * (1.0f / (P_DIM * 2.0f * K_DIM));
    }
  }
}

extern "C" void kernel_launch(void* const* d_in, const int* in_sizes, int n_in,
                              void* d_out, int out_size, void* d_ws, size_t ws_size,
                              hipStream_t stream) {
  const float* t2 = (const float*)d_in[0];
  const float* t1 = (const float*)d_in[1];
  const int* idx  = (const int*)d_in[2];
  float* ws = (float*)d_ws;
  float*  diag   = ws + OFF_DIAG;
  ushort* Ebf    = (ushort*)(ws + OFF_EBF);
  ushort* ETbf   = (ushort*)(ws + OFF_ETBF);
  float*  part   = ws + OFF_PART;
  int*    bar    = (int*)(ws + OFF_BAR);

  gram_exp_kernel<<<512, 256, 0, stream>>>(t2, t1, Ebf, ETbf, diag, bar);
  denom_loss_kernel<<<64, 1024, 0, stream>>>(Ebf, ETbf, idx, diag, part, bar,
                                             (float*)d_out);
}